// Round 1
// baseline (209.622 us; speedup 1.0000x reference)
//
#include <hip/hip_runtime.h>
#include <hip/hip_bf16.h>
#include <stdint.h>

#define N_MODELS 16
#define IN_F 1024
#define OUT_F 1024
#define N_TOK 8192

#define BM 128
#define BN 128
#define BK 32
#define LDA 40   // u16 stride: 80 B rows -> 2-way (free) bank pattern on b128 reads

using us4   = __attribute__((ext_vector_type(4))) unsigned short;
using s16x8 = __attribute__((ext_vector_type(8))) short;
using f32x4 = __attribute__((ext_vector_type(4))) float;

__device__ __forceinline__ unsigned short f2bf(float f) {
    union { float f; uint32_t u; } v;
    v.f = f;
    uint32_t u = v.u;
    u += 0x7fffu + ((u >> 16) & 1u);   // RNE
    return (unsigned short)(u >> 16);
}

// ---------------- kernel 1: bucket tokens by expert ----------------
__global__ void bucket_kernel(const int* __restrict__ idxs,
                              int* __restrict__ perm,
                              int* __restrict__ offs,      // [17]
                              int* __restrict__ tile_off)  // [17]
{
    __shared__ int cnt[N_MODELS];
    __shared__ int cur[N_MODELS];
    int t = threadIdx.x;
    if (t < N_MODELS) cnt[t] = 0;
    __syncthreads();
    for (int i = t; i < N_TOK; i += 256) atomicAdd(&cnt[idxs[i]], 1);
    __syncthreads();
    if (t == 0) {
        int o = 0, to = 0;
        for (int e = 0; e < N_MODELS; ++e) {
            offs[e] = o; tile_off[e] = to; cur[e] = o;
            to += (cnt[e] + BM - 1) / BM;
            o  += cnt[e];
        }
        offs[N_MODELS] = o; tile_off[N_MODELS] = to;
    }
    __syncthreads();
    for (int i = t; i < N_TOK; i += 256) {
        int e = idxs[i];
        int p = atomicAdd(&cur[e], 1);
        perm[p] = i;
    }
}

// ---------------- kernel 2: w fp32 [e][k][n] -> bf16 [e][n][k] ----------------
#define TT 64
__global__ void transpose_w_kernel(const float* __restrict__ w,
                                   unsigned short* __restrict__ wT)
{
    __shared__ unsigned short tile[TT][TT + 8];
    int e  = blockIdx.z;
    int n0 = blockIdx.y * TT;
    int k0 = blockIdx.x * TT;
    int t  = threadIdx.x;
    const float* wp = w + (size_t)e * IN_F * OUT_F;
    int c4 = (t & 15) * 4;
    int r  = t >> 4;  // 0..15
#pragma unroll
    for (int i = 0; i < 4; ++i) {
        int k = r + i * 16;
        const float4 v = *(const float4*)(wp + (size_t)(k0 + k) * OUT_F + n0 + c4);
        us4 pk;
        pk.x = f2bf(v.x); pk.y = f2bf(v.y); pk.z = f2bf(v.z); pk.w = f2bf(v.w);
        *(us4*)(&tile[k][c4]) = pk;
    }
    __syncthreads();
#pragma unroll
    for (int i = 0; i < 4; ++i) {
        int n = r + i * 16;
        us4 pk;
        pk.x = tile[c4 + 0][n];
        pk.y = tile[c4 + 1][n];
        pk.z = tile[c4 + 2][n];
        pk.w = tile[c4 + 3][n];
        *(us4*)(wT + (size_t)e * IN_F * OUT_F + (size_t)(n0 + n) * IN_F + k0 + c4) = pk;
    }
}

// ---------------- kernel 3: grouped GEMM + bias + relu ----------------
__global__ __launch_bounds__(256)
void gemm_kernel(const float* __restrict__ x,
                 const unsigned short* __restrict__ wT,
                 const float* __restrict__ bias,
                 const int* __restrict__ perm,
                 const int* __restrict__ offs,
                 const int* __restrict__ tile_off,
                 float* __restrict__ out)
{
    __shared__ unsigned short As[BM * LDA];
    __shared__ unsigned short Bs[BN * LDA];
    __shared__ int   permS[BM];
    __shared__ float biasS[BN];
    __shared__ int   toS[N_MODELS + 1];

    int t  = threadIdx.x;
    int bt = blockIdx.y;
    int n0 = blockIdx.x * BN;

    if (t <= N_MODELS) toS[t] = tile_off[t];
    __syncthreads();
    if (bt >= toS[N_MODELS]) return;   // uniform

    int e = 0;
    while (toS[e + 1] <= bt) ++e;
    int mt_blk = bt - toS[e];
    int sBeg = offs[e];
    int sEnd = offs[e + 1];
    int s0 = sBeg + mt_blk * BM;
    int mValid = sEnd - s0; if (mValid > BM) mValid = BM;

    if (t < BM) permS[t] = (s0 + t < sEnd) ? perm[s0 + t] : 0;
    if (t < BN) biasS[t] = bias[(size_t)e * OUT_F + n0 + t];
    __syncthreads();

    const unsigned short* wTp = wT + (size_t)e * IN_F * OUT_F;

    f32x4 acc[4][4];
#pragma unroll
    for (int i = 0; i < 4; ++i)
#pragma unroll
        for (int j = 0; j < 4; ++j)
            acc[i][j] = (f32x4){0.f, 0.f, 0.f, 0.f};

    int lane = t & 63;
    int w    = t >> 6;
    int wm   = (w >> 1) * 64;
    int wn   = (w & 1) * 64;
    int m    = lane & 15;
    int q    = lane >> 4;

    int ar   = t >> 3;   // + i*32
    int apos = t & 7;    // 4-float chunk within 32-float k window
    int br   = t >> 2;   // + i*64
    int bpos = t & 3;    // 8-bf16 chunk

    for (int k0 = 0; k0 < IN_F; k0 += BK) {
        // stage A: x fp32 (gathered rows) -> bf16 LDS
#pragma unroll
        for (int i = 0; i < 4; ++i) {
            int r = ar + i * 32;
            int tok = permS[r];
            const float4 v = *(const float4*)(x + (size_t)tok * IN_F + k0 + apos * 4);
            us4 pk;
            pk.x = f2bf(v.x); pk.y = f2bf(v.y); pk.z = f2bf(v.z); pk.w = f2bf(v.w);
            *(us4*)(&As[r * LDA + apos * 4]) = pk;
        }
        // stage B: wT bf16 -> LDS
#pragma unroll
        for (int i = 0; i < 2; ++i) {
            int r = br + i * 64;
            s16x8 v = *(const s16x8*)(wTp + (size_t)(n0 + r) * IN_F + k0 + bpos * 8);
            *(s16x8*)(&Bs[r * LDA + bpos * 8]) = v;
        }
        __syncthreads();

        s16x8 af[4], bfr[4];
#pragma unroll
        for (int mt = 0; mt < 4; ++mt)
            af[mt] = *(const s16x8*)(&As[(wm + mt * 16 + m) * LDA + q * 8]);
#pragma unroll
        for (int nt = 0; nt < 4; ++nt)
            bfr[nt] = *(const s16x8*)(&Bs[(wn + nt * 16 + m) * LDA + q * 8]);
#pragma unroll
        for (int mt = 0; mt < 4; ++mt)
#pragma unroll
            for (int nt = 0; nt < 4; ++nt)
                acc[mt][nt] = __builtin_amdgcn_mfma_f32_16x16x32_bf16(
                    af[mt], bfr[nt], acc[mt][nt], 0, 0, 0);
        __syncthreads();
    }

    // epilogue: bias + relu, scatter rows by perm
#pragma unroll
    for (int mt = 0; mt < 4; ++mt) {
        int rbase = wm + mt * 16 + q * 4;
#pragma unroll
        for (int i = 0; i < 4; ++i) {
            int r = rbase + i;
            if (r < mValid) {
                int tok = permS[r];
                float* orow = out + (size_t)tok * OUT_F + n0;
#pragma unroll
                for (int nt = 0; nt < 4; ++nt) {
                    int c = wn + nt * 16 + m;
                    float v = acc[mt][nt][i] + biasS[c];
                    orow[c] = v > 0.f ? v : 0.f;
                }
            }
        }
    }
}

extern "C" void kernel_launch(void* const* d_in, const int* in_sizes, int n_in,
                              void* d_out, int out_size, void* d_ws, size_t ws_size,
                              hipStream_t stream) {
    const float* x    = (const float*)d_in[0];
    const int*   idxs = (const int*)d_in[1];
    const float* w    = (const float*)d_in[2];
    const float* b    = (const float*)d_in[3];
    float* out = (float*)d_out;

    // ws layout: wT bf16 [16*1024*1024] (32 MB) | perm [8192] | offs [17] | tile_off [17]
    unsigned short* wT = (unsigned short*)d_ws;
    int* perm     = (int*)((char*)d_ws + (size_t)N_MODELS * IN_F * OUT_F * sizeof(unsigned short));
    int* offs     = perm + N_TOK;
    int* tile_off = offs + (N_MODELS + 1);

    bucket_kernel<<<1, 256, 0, stream>>>(idxs, perm, offs, tile_off);
    transpose_w_kernel<<<dim3(IN_F / TT, OUT_F / TT, N_MODELS), 256, 0, stream>>>(w, wT);
    // max total m-tiles = 64 + 15 = 79 -> grid.y = 80; inactive tiles exit early
    gemm_kernel<<<dim3(OUT_F / BN, 80), 256, 0, stream>>>(x, wT, b, perm, offs, tile_off, out);
}

// Round 2
// 194.506 us; speedup vs baseline: 1.0777x; 1.0777x over previous
//
#include <hip/hip_runtime.h>
#include <hip/hip_bf16.h>
#include <stdint.h>

#define N_MODELS 16
#define IN_F 1024
#define OUT_F 1024
#define N_TOK 8192
#define MAX_MT 80          // max m-tiles: 64 full + up to 15 fragmentation, padded

typedef unsigned short u16;
using us4   = __attribute__((ext_vector_type(4))) unsigned short;
using s16x8 = __attribute__((ext_vector_type(8))) short;
using f32x4 = __attribute__((ext_vector_type(4))) float;

__device__ __forceinline__ u16 f2bf(float f) {
    union { float f; uint32_t u; } v;
    v.f = f;
    uint32_t u = v.u;
    u += 0x7fffu + ((u >> 16) & 1u);   // RNE
    return (u16)(u >> 16);
}

__device__ __forceinline__ void gload16(const u16* g, u16* l) {
    // async global->LDS DMA, 16 B/lane; LDS dest = wave-uniform base + lane*16
    __builtin_amdgcn_global_load_lds(
        (const __attribute__((address_space(1))) void*)g,
        (__attribute__((address_space(3))) void*)l, 16, 0, 0);
}

// ---------------- kernel 1: bucket tokens by expert ----------------
__global__ void bucket_kernel(const int* __restrict__ idxs,
                              int* __restrict__ perm,
                              int* __restrict__ offs,      // [17]
                              int* __restrict__ tile_off)  // [17]
{
    __shared__ int cnt[N_MODELS];
    __shared__ int cur[N_MODELS];
    int t = threadIdx.x;
    if (t < N_MODELS) cnt[t] = 0;
    __syncthreads();
    for (int i = t; i < N_TOK; i += 256) atomicAdd(&cnt[idxs[i]], 1);
    __syncthreads();
    if (t == 0) {
        int o = 0, to = 0;
        for (int e = 0; e < N_MODELS; ++e) {
            offs[e] = o; tile_off[e] = to; cur[e] = o;
            to += (cnt[e] + 127) / 128;
            o  += cnt[e];
        }
        offs[N_MODELS] = o; tile_off[N_MODELS] = to;
    }
    __syncthreads();
    for (int i = t; i < N_TOK; i += 256) {
        int e = idxs[i];
        int p = atomicAdd(&cur[e], 1);
        perm[p] = i;
    }
}

// ---------------- kernel 2: prep — build frag-major bf16 tile images ----------------
// wT layout (u16): ((((e*8 + nt)*32 + kb)*4 + q)*128 + n)*8 + j   (kb: 32-k block, q: k-octet)
// xg layout (u16): ((mt*32 + kb)*4096) + q*1024 + r*8 + j          (r: row within 128-tile)
#define WBLOCKS (16*8*16)   // (e, ntile, kgroup64) = 2048
#define SH_S 132            // u16 stride for 64x128 transpose tile (8B-aligned rows, uniform banks)

__global__ __launch_bounds__(256)
void prep_kernel(const float* __restrict__ w, const float* __restrict__ x,
                 const int* __restrict__ perm, const int* __restrict__ offs,
                 const int* __restrict__ tile_off,
                 u16* __restrict__ wT, u16* __restrict__ xg)
{
    __shared__ u16 sh[64 * SH_S];   // 16.5 KB (x-path uses first 4096)
    int t  = threadIdx.x;
    int bx = blockIdx.x;

    if (bx < WBLOCKS) {
        // ---- w fp32 [k][n] -> wT bf16 frag-major ----
        int e  = bx >> 7;
        int nt = (bx >> 4) & 7;
        int kg = bx & 15;            // 64-k group
        const float* wp = w + (size_t)e * 1048576 + (size_t)kg * 65536 + nt * 128;
        int n4  = t & 31;
        int kr0 = t >> 5;
#pragma unroll
        for (int p = 0; p < 8; ++p) {
            int kr = kr0 + p * 8;    // 0..63
            const float4 v = *(const float4*)(wp + (size_t)kr * 1024 + n4 * 4);
            us4 pk; pk.x = f2bf(v.x); pk.y = f2bf(v.y); pk.z = f2bf(v.z); pk.w = f2bf(v.w);
            *(us4*)(&sh[kr * SH_S + n4 * 4]) = pk;
        }
        __syncthreads();
        int n  = t & 127;
        int qh = t >> 7;             // 0..1
        u16* outb = wT + ((size_t)(e * 8 + nt) * 32) * 4096;
#pragma unroll
        for (int oct = 0; oct < 4; ++oct) {
            int ko = qh + oct * 2;       // k-octet within the 64 (0..7)
            int kb = kg * 2 + (ko >> 2); // global 32-k block
            int q  = ko & 3;
            s16x8 v;
#pragma unroll
            for (int j = 0; j < 8; ++j) v[j] = (short)sh[(ko * 8 + j) * SH_S + n];
            *(s16x8*)(outb + ((size_t)kb * 4 + q) * 1024 + n * 8) = v;
        }
    } else {
        // ---- x fp32 gathered by perm -> xg bf16 frag-major ----
        int bx2 = bx - WBLOCKS;      // 0..639
        int mt = bx2 >> 3;
        int kg = bx2 & 7;            // 128-k group
        int total = tile_off[16];
        if (mt >= total) return;
        int e = 0;
        while (tile_off[e + 1] <= mt) ++e;
        int s0   = offs[e] + (mt - tile_off[e]) * 128;
        int sEnd = offs[e + 1];
        int r0   = t >> 3;           // +i*32
        int apos = t & 7;
        int toks[4];
#pragma unroll
        for (int i = 0; i < 4; ++i) {
            int r = r0 + i * 32;
            toks[i] = (s0 + r < sEnd) ? perm[s0 + r] : -1;
        }
        u16* outx = xg + (size_t)mt * 32 * 4096;
        for (int kb4 = 0; kb4 < 4; ++kb4) {
            int kb = kg * 4 + kb4;
#pragma unroll
            for (int i = 0; i < 4; ++i) {
                int r = r0 + i * 32;
                int k = kb * 32 + apos * 4;
                float4 v;
                if (toks[i] >= 0) v = *(const float4*)(x + (size_t)toks[i] * 1024 + k);
                else              v = make_float4(0.f, 0.f, 0.f, 0.f);
                us4 pk; pk.x = f2bf(v.x); pk.y = f2bf(v.y); pk.z = f2bf(v.z); pk.w = f2bf(v.w);
                *(us4*)(&sh[(apos >> 1) * 1024 + r * 8 + (apos & 1) * 4]) = pk;
            }
            __syncthreads();
#pragma unroll
            for (int i = 0; i < 2; ++i) {
                int c = t + i * 256;     // 16B chunk id, 512 total
                *(s16x8*)(outx + (size_t)kb * 4096 + c * 8) = *(const s16x8*)(&sh[c * 8]);
            }
            __syncthreads();
        }
    }
}

// ---------------- kernel 3: grouped GEMM + bias + relu (m97 structure) ----------------
__global__ __launch_bounds__(256)
void gemm_kernel(const u16* __restrict__ xg, const u16* __restrict__ wT,
                 const float* __restrict__ bias,
                 const int* __restrict__ perm, const int* __restrict__ offs,
                 const int* __restrict__ tile_off,
                 float* __restrict__ out)
{
    __shared__ u16 As[4096];
    __shared__ u16 Bs[4096];
    __shared__ int   permS[128];
    __shared__ float biasS[128];
    __shared__ int   toS[N_MODELS + 1];

    int t  = threadIdx.x;
    int bt = blockIdx.y;            // flat m-tile id
    int nt = blockIdx.x;            // n-tile id

    if (t <= N_MODELS) toS[t] = tile_off[t];
    __syncthreads();
    if (bt >= toS[N_MODELS]) return;   // uniform

    int e = 0;
    while (toS[e + 1] <= bt) ++e;
    int s0   = offs[e] + (bt - toS[e]) * 128;
    int sEnd = offs[e + 1];
    int mValid = sEnd - s0; if (mValid > 128) mValid = 128;

    if (t < 128) {
        permS[t] = (s0 + t < sEnd) ? perm[s0 + t] : 0;
        biasS[t] = bias[(size_t)e * OUT_F + nt * 128 + t];
    }

    const u16* atile = xg + (size_t)bt * 32 * 4096;
    const u16* btile = wT + ((size_t)(e * 8 + nt) * 32) * 4096;

    int lane = t & 63;
    int wv   = t >> 6;
    int wm   = (wv >> 1) * 64;
    int wn   = (wv & 1) * 64;
    int m    = lane & 15;
    int q    = lane >> 4;

    f32x4 acc[4][4];
#pragma unroll
    for (int i = 0; i < 4; ++i)
#pragma unroll
        for (int j = 0; j < 4; ++j)
            acc[i][j] = (f32x4){0.f, 0.f, 0.f, 0.f};

    int c = wv * 2;   // this wave's 1 KB chunk base (8 chunks per 8 KB tile)

    for (int kb = 0; kb < 32; ++kb) {
        const u16* ga = atile + kb * 4096;
        const u16* gb = btile + kb * 4096;
        gload16(ga + (c    ) * 512 + lane * 8, &As[(c    ) * 512]);
        gload16(ga + (c + 1) * 512 + lane * 8, &As[(c + 1) * 512]);
        gload16(gb + (c    ) * 512 + lane * 8, &Bs[(c    ) * 512]);
        gload16(gb + (c + 1) * 512 + lane * 8, &Bs[(c + 1) * 512]);
        __syncthreads();

        s16x8 af[4], bf[4];
#pragma unroll
        for (int mt2 = 0; mt2 < 4; ++mt2)
            af[mt2] = *(const s16x8*)(&As[q * 1024 + (wm + mt2 * 16 + m) * 8]);
#pragma unroll
        for (int nt2 = 0; nt2 < 4; ++nt2)
            bf[nt2] = *(const s16x8*)(&Bs[q * 1024 + (wn + nt2 * 16 + m) * 8]);
#pragma unroll
        for (int mt2 = 0; mt2 < 4; ++mt2)
#pragma unroll
            for (int nt2 = 0; nt2 < 4; ++nt2)
                acc[mt2][nt2] = __builtin_amdgcn_mfma_f32_16x16x32_bf16(
                    af[mt2], bf[nt2], acc[mt2][nt2], 0, 0, 0);
        __syncthreads();
    }

    // epilogue: bias + relu, scatter rows by perm
#pragma unroll
    for (int mt2 = 0; mt2 < 4; ++mt2) {
        int rbase = wm + mt2 * 16 + q * 4;
#pragma unroll
        for (int i = 0; i < 4; ++i) {
            int r = rbase + i;
            if (r < mValid) {
                int tok = permS[r];
                float* orow = out + (size_t)tok * OUT_F + nt * 128;
#pragma unroll
                for (int nt2 = 0; nt2 < 4; ++nt2) {
                    int col = wn + nt2 * 16 + m;
                    float v = acc[mt2][nt2][i] + biasS[col];
                    orow[col] = v > 0.f ? v : 0.f;
                }
            }
        }
    }
}

extern "C" void kernel_launch(void* const* d_in, const int* in_sizes, int n_in,
                              void* d_out, int out_size, void* d_ws, size_t ws_size,
                              hipStream_t stream) {
    const float* x    = (const float*)d_in[0];
    const int*   idxs = (const int*)d_in[1];
    const float* w    = (const float*)d_in[2];
    const float* b    = (const float*)d_in[3];
    float* out = (float*)d_out;

    // ws layout: wT u16[16M] (32 MB) | xg u16[80*32*4096] (20 MB) | perm | offs | tile_off
    u16* wT = (u16*)d_ws;
    u16* xg = wT + (size_t)N_MODELS * IN_F * OUT_F;
    int* perm     = (int*)(xg + (size_t)MAX_MT * 32 * 4096);
    int* offs     = perm + N_TOK;
    int* tile_off = offs + (N_MODELS + 1);

    bucket_kernel<<<1, 256, 0, stream>>>(idxs, perm, offs, tile_off);
    prep_kernel<<<WBLOCKS + 640, 256, 0, stream>>>(w, x, perm, offs, tile_off, wT, xg);
    gemm_kernel<<<dim3(8, MAX_MT), 256, 0, stream>>>(xg, wT, b, perm, offs, tile_off, out);
}